// Round 1
// baseline (344.399 us; speedup 1.0000x reference)
//
#include <hip/hip_runtime.h>

// GCN_FFN: out = relu( (adj * softmax(XX^T/sqrt(F)) / sqrt(F)) @ X @ W^T )
// per bt-slice (bt = b*T+t), X slice = x[b,:,t,:] (N=512 rows, F=256).
// Fully fused flash-attention-style kernel, f16 MFMA (16x16x32), f32 accum.

typedef __attribute__((ext_vector_type(8))) _Float16 h16x8;
typedef __attribute__((ext_vector_type(4))) float f32x4;
typedef __attribute__((ext_vector_type(4))) unsigned short us4;

#define MFMA16(a, b, c) __builtin_amdgcn_mfma_f32_16x16x32_f16((a), (b), (c), 0, 0, 0)

__device__ __forceinline__ unsigned short f2h(float f) {
    _Float16 h = (_Float16)f;
    return __builtin_bit_cast(unsigned short, h);
}

__device__ __forceinline__ void st4(unsigned short* p, unsigned short a, unsigned short b,
                                    unsigned short c, unsigned short d) {
    us4 v = {a, b, c, d};
    *(us4*)p = v;
}

namespace {
constexpr int Nn = 512;   // nodes
constexpr int TT = 64;    // time
constexpr int FF = 256;   // features
constexpr int KLD = 264;  // kt row stride (elems), 528B = 33*16
constexpr int TLD = 72;   // vt/pb row stride, 144B = 9*16
constexpr int WLD = 136;  // wc row stride, 272B = 17*16
constexpr float SCALE = 0.0625f;  // 1/sqrt(256)
constexpr float L2E = 1.44269504088896340736f;
}

__global__ __launch_bounds__(256, 2) void gcn_fused(const float* __restrict__ x,
                                                    const float* __restrict__ adj,
                                                    const float* __restrict__ W,
                                                    float* __restrict__ out) {
    // LDS: main phase {kt 64x264, vt 256x72} / theta phase {hb 64x264, wc 128x136}
    __shared__ alignas(16) union {
        struct { unsigned short kt[64 * KLD]; unsigned short vt[256 * TLD]; } m;
        struct { unsigned short hb[64 * KLD]; unsigned short wc[128 * WLD]; } t;
    } sm;
    __shared__ alignas(16) unsigned short pb[4 * 16 * TLD];  // per-wave P' bounce

    const int tid = threadIdx.x;
    const int w  = tid >> 6;   // wave 0..3
    const int l  = tid & 63;   // lane
    const int lg = l >> 4;     // lane group 0..3
    const int lc = l & 15;     // lane col 0..15

    // XCD swizzle: keep all 8 q-tiles of one bt on one XCD (2048 = 8*256)
    const int lb = (blockIdx.x & 7) * 256 + (blockIdx.x >> 3);
    const int bt = lb >> 3;        // 0..255
    const int qt = lb & 7;         // q-tile 0..7
    const int b  = bt >> 6;        // batch
    const int tt = bt & 63;        // time
    const int qbase = qt * 64;

    const float* xbt = x + (size_t)b * (Nn * TT * FF) + (size_t)tt * FF;  // + n*TT*FF + f

    // ---- Q fragments: rows qbase+16w+lc, pre-scaled by 1/16 ----
    h16x8 qf[8];
    {
        const float* qp = xbt + (size_t)(qbase + 16 * w + lc) * (TT * FF);
        #pragma unroll
        for (int ks = 0; ks < 8; ++ks) {
            const float* p = qp + ks * 32 + lg * 8;
            float4 a = *(const float4*)(p);
            float4 c = *(const float4*)(p + 4);
            h16x8 v;
            v[0] = (_Float16)(a.x * SCALE); v[1] = (_Float16)(a.y * SCALE);
            v[2] = (_Float16)(a.z * SCALE); v[3] = (_Float16)(a.w * SCALE);
            v[4] = (_Float16)(c.x * SCALE); v[5] = (_Float16)(c.y * SCALE);
            v[6] = (_Float16)(c.z * SCALE); v[7] = (_Float16)(c.w * SCALE);
            qf[ks] = v;
        }
    }

    f32x4 acc[16];
    #pragma unroll
    for (int i = 0; i < 16; ++i) { f32x4 z = {0.f, 0.f, 0.f, 0.f}; acc[i] = z; }
    float mrow[4] = {-1e30f, -1e30f, -1e30f, -1e30f};
    float lrow[4] = {0.f, 0.f, 0.f, 0.f};

    const int fb  = tid & 63;   // staging f-block (f0 = fb*4)
    const int mb0 = tid >> 6;   // staging m-block base

    for (int kt2 = 0; kt2 < 8; ++kt2) {
        const int kbase = kt2 * 64;

        // ---- stage key tile: kt[m][f] (row-major) and vt[f][m] (transposed) ----
        #pragma unroll
        for (int i = 0; i < 4; ++i) {
            const int m0 = (mb0 * 4 + i) * 4;  // 0..60
            const int f0 = fb * 4;             // 0..252
            const float* p = xbt + (size_t)(kbase + m0) * (TT * FF) + f0;
            float4 r0 = *(const float4*)(p);
            float4 r1 = *(const float4*)(p + TT * FF);
            float4 r2 = *(const float4*)(p + 2 * TT * FF);
            float4 r3 = *(const float4*)(p + 3 * TT * FF);
            unsigned short a0=f2h(r0.x),a1=f2h(r0.y),a2=f2h(r0.z),a3=f2h(r0.w);
            unsigned short b0=f2h(r1.x),b1=f2h(r1.y),b2=f2h(r1.z),b3=f2h(r1.w);
            unsigned short c0=f2h(r2.x),c1=f2h(r2.y),c2=f2h(r2.z),c3=f2h(r2.w);
            unsigned short d0=f2h(r3.x),d1=f2h(r3.y),d2=f2h(r3.z),d3=f2h(r3.w);
            st4(&sm.m.kt[(m0 + 0) * KLD + f0], a0, a1, a2, a3);
            st4(&sm.m.kt[(m0 + 1) * KLD + f0], b0, b1, b2, b3);
            st4(&sm.m.kt[(m0 + 2) * KLD + f0], c0, c1, c2, c3);
            st4(&sm.m.kt[(m0 + 3) * KLD + f0], d0, d1, d2, d3);
            st4(&sm.m.vt[(f0 + 0) * TLD + m0], a0, b0, c0, d0);
            st4(&sm.m.vt[(f0 + 1) * TLD + m0], a1, b1, c1, d1);
            st4(&sm.m.vt[(f0 + 2) * TLD + m0], a2, b2, c2, d2);
            st4(&sm.m.vt[(f0 + 3) * TLD + m0], a3, b3, c3, d3);
        }
        __syncthreads();

        // ---- S = Q K^T (wave: 16 rows x 64 cols) ----
        f32x4 s[4];
        #pragma unroll
        for (int jt = 0; jt < 4; ++jt) {
            f32x4 sa = {0.f, 0.f, 0.f, 0.f};
            #pragma unroll
            for (int ks = 0; ks < 8; ++ks) {
                h16x8 bf = *(const h16x8*)&sm.m.kt[(jt * 16 + lc) * KLD + ks * 32 + lg * 8];
                sa = MFMA16(qf[ks], bf, sa);
            }
            s[jt] = sa;
        }

        // ---- online softmax (wave-local; lane owns rows 4*lg+r) ----
        float mnew[4], resc[4], rs[4];
        #pragma unroll
        for (int r = 0; r < 4; ++r) {
            float mx = fmaxf(fmaxf(s[0][r], s[1][r]), fmaxf(s[2][r], s[3][r]));
            mx = fmaxf(mx, __shfl_xor(mx, 1));
            mx = fmaxf(mx, __shfl_xor(mx, 2));
            mx = fmaxf(mx, __shfl_xor(mx, 4));
            mx = fmaxf(mx, __shfl_xor(mx, 8));
            mnew[r] = fmaxf(mrow[r], mx);
            resc[r] = exp2f((mrow[r] - mnew[r]) * L2E);
            mrow[r] = mnew[r];
            rs[r] = 0.f;
        }
        const int qrow0 = qbase + 16 * w + 4 * lg;
        #pragma unroll
        for (int jt = 0; jt < 4; ++jt) {
            const int mcol = kbase + jt * 16 + lc;
            #pragma unroll
            for (int r = 0; r < 4; ++r) {
                float p = exp2f((s[jt][r] - mnew[r]) * L2E);
                rs[r] += p;
                float pp = p * adj[(qrow0 + r) * Nn + mcol];
                pb[w * (16 * TLD) + (4 * lg + r) * TLD + jt * 16 + lc] = f2h(pp);
            }
        }
        #pragma unroll
        for (int r = 0; r < 4; ++r) {
            float t0 = rs[r];
            t0 += __shfl_xor(t0, 1);
            t0 += __shfl_xor(t0, 2);
            t0 += __shfl_xor(t0, 4);
            t0 += __shfl_xor(t0, 8);
            lrow[r] = lrow[r] * resc[r] + t0;
        }
        #pragma unroll
        for (int ft = 0; ft < 16; ++ft) {
            #pragma unroll
            for (int r = 0; r < 4; ++r) acc[ft][r] *= resc[r];
        }

        // ---- acc += P' @ V  (V = key tile, read m-contiguous from vt) ----
        #pragma unroll
        for (int ks = 0; ks < 2; ++ks) {
            h16x8 pa = *(const h16x8*)&pb[w * (16 * TLD) + lc * TLD + ks * 32 + lg * 8];
            #pragma unroll
            for (int ft = 0; ft < 16; ++ft) {
                h16x8 bv = *(const h16x8*)&sm.m.vt[(ft * 16 + lc) * TLD + ks * 32 + lg * 8];
                acc[ft] = MFMA16(pa, bv, acc[ft]);
            }
        }
        __syncthreads();
    }

    // ---- h = acc * (SCALE / l) -> hb (f16), wave-local rows ----
    {
        float c0[4];
        #pragma unroll
        for (int r = 0; r < 4; ++r) c0[r] = SCALE / lrow[r];
        #pragma unroll
        for (int ft = 0; ft < 16; ++ft) {
            #pragma unroll
            for (int r = 0; r < 4; ++r) {
                sm.t.hb[(w * 16 + 4 * lg + r) * KLD + ft * 16 + lc] = f2h(acc[ft][r] * c0[r]);
            }
        }
    }

    // ---- y = h @ W^T, relu, store ----
    const int or0 = tid >> 5;  // 0..7
    const int fc  = tid & 31;  // 0..31
    for (int oh = 0; oh < 2; ++oh) {
        f32x4 y[8];
        #pragma unroll
        for (int i = 0; i < 8; ++i) { f32x4 z = {0.f, 0.f, 0.f, 0.f}; y[i] = z; }
        for (int fh = 0; fh < 2; ++fh) {
            __syncthreads();  // protect wc from previous readers
            #pragma unroll
            for (int i = 0; i < 16; ++i) {
                const int o = or0 * 16 + i;
                float4 v = *(const float4*)&W[(size_t)(oh * 128 + o) * FF + fh * 128 + fc * 4];
                st4(&sm.t.wc[o * WLD + fc * 4], f2h(v.x), f2h(v.y), f2h(v.z), f2h(v.w));
            }
            __syncthreads();
            h16x8 ha[4];
            #pragma unroll
            for (int ks = 0; ks < 4; ++ks)
                ha[ks] = *(const h16x8*)&sm.t.hb[(w * 16 + lc) * KLD + fh * 128 + ks * 32 + lg * 8];
            #pragma unroll
            for (int ot = 0; ot < 8; ++ot) {
                #pragma unroll
                for (int ks = 0; ks < 4; ++ks) {
                    h16x8 bw = *(const h16x8*)&sm.t.wc[(ot * 16 + lc) * WLD + ks * 32 + lg * 8];
                    y[ot] = MFMA16(ha[ks], bw, y[ot]);
                }
            }
        }
        const int qrow = qbase + 16 * w + 4 * lg;
        #pragma unroll
        for (int ot = 0; ot < 8; ++ot) {
            const int o = oh * 128 + ot * 16 + lc;
            #pragma unroll
            for (int r = 0; r < 4; ++r) {
                float v = y[ot][r];
                out[((size_t)(b * Nn + qrow + r) * TT + tt) * FF + o] = v > 0.f ? v : 0.f;
            }
        }
    }
}

extern "C" void kernel_launch(void* const* d_in, const int* in_sizes, int n_in,
                              void* d_out, int out_size, void* d_ws, size_t ws_size,
                              hipStream_t stream) {
    const float* x   = (const float*)d_in[0];
    const float* adj = (const float*)d_in[1];
    const float* w   = (const float*)d_in[2];
    float* out       = (float*)d_out;
    (void)in_sizes; (void)n_in; (void)out_size; (void)d_ws; (void)ws_size;
    gcn_fused<<<dim3(2048), dim3(256), 0, stream>>>(x, adj, w, out);
}